// Round 1
// 113.360 us; speedup vs baseline: 1.0143x; 1.0143x over previous
//
#include <hip/hip_runtime.h>

// Soft VQ encoding, fused bf16-MFMA implementation. Round 9.
//   X:(8,16384,128) fp32, C:(128,128) fp32, S:(128) fp32 -> E:(8,128,128) fp32
// r9 changes vs r8 (115us):
//  (1) matmul1 operand swap: compute D^T[n][cw] = X * C^T with A = cu (regs,
//      free) and B = the SAME sCb bytes used as C^T-fragments. Lane now holds
//      (n = quad*4+r, cw = mt*16+l15). This makes:
//        - sST reads one broadcast float2 per mt (8 b64, conflict-free)
//          instead of 16 b128/wave/chunk  (-1 KB/n on the LDS pipe);
//        - A->LDS writes 8 packed ds_write_b64 (4 consecutive n per lane)
//          instead of 32 scalar ds_write_b16 (1/4 the LDS write instrs);
//        - costs: ls-reduce now a 4-wide xor-tree over l15 (16 shfl vs 2),
//          4 shfl to redistribute x2, 3 extra rcp. VALU-cheap, VGPR-neutral
//          (no hoists -- r7's >128-arch-VGPR spill cliff stays untouched).
//  (2) vq_reduce: thread-per-float2, grid 512x128 (1024 waves = 4/CU),
//      unroll 16 -> ~16KB/CU loads in flight (covers ~900cy HBM latency at
//      fair-share BW). Was 512x64 unroll-8 = marginal latency coverage.
// Top-5 rocprof dispatches are harness 256MiB ws-poison fills (~41.5us each);
// both our kernels are < 41us. This round's delta disambiguates how much of
// the 115us is fill vs kernel.

#define NN   16384
#define ND   128
#define NK   128
#define NC   64        // rows per chunk
#define TT   4         // chunks per block
#define BPB  64        // blocks per batch (grid = 8*BPB = 512)
#define CBP  136       // sCb row stride (bf16 elems), 272B -> b128-aligned, 2-way banks
#define XTP  72        // X^T LDS row stride, 144B (stride%32banks=4 -> spreads rows)
#define ATP  72        // A^T LDS row stride, 144B

typedef __bf16 bf16x8 __attribute__((ext_vector_type(8)));
typedef float  f32x4  __attribute__((ext_vector_type(4)));

union CU  { __bf16 b[8]; unsigned short u[8]; bf16x8 v; };
union HH4 { __bf16 b[4]; ushort4 s; };

__device__ __forceinline__ float bf2f(unsigned short u) {
    return __uint_as_float(((unsigned int)u) << 16);
}

// ---------------- kernel 1: fused main ----------------
__global__ __launch_bounds__(256, 2) void vq_main(
    const float* __restrict__ Xg, const float* __restrict__ Cg,
    const float* __restrict__ Sg, unsigned short* __restrict__ Pg)
{
    __shared__ __align__(16) unsigned short sCb[NK * CBP];   // 34816 B
    __shared__ __align__(16) unsigned short sXT[ND * XTP];   // 18432 B
    __shared__ __align__(16) unsigned short sAt[NK * ATP];   // 18432 B
    __shared__ __align__(16) float2 sST[NK];                 // 1 KB
    __shared__ __align__(16) float  sC2[NK];                 // 512 B

    const int tid  = threadIdx.x;
    const int lane = tid & 63;
    const int wave = tid >> 6;
    const int l15  = lane & 15;
    const int quad = lane >> 4;
    const int bid  = blockIdx.x;
    const int b    = bid >> 6;        // batch
    const int bg   = bid & (BPB - 1); // block-in-batch

    // ---- prologue: stage C -> bf16 LDS, C2 row sums, ST = {S, S*C2} ----
    #pragma unroll
    for (int it = 0; it < 16; ++it) {
        int flat = it * 256 + tid;
        int row  = flat >> 5;          // 0..127
        int c4   = flat & 31;
        float4 v = reinterpret_cast<const float4*>(Cg)[row * 32 + c4];
        HH4 h;
        h.b[0] = (__bf16)v.x; h.b[1] = (__bf16)v.y;
        h.b[2] = (__bf16)v.z; h.b[3] = (__bf16)v.w;
        *reinterpret_cast<ushort4*>(&sCb[row * CBP + c4 * 4]) = h.s;
        float ss = v.x*v.x + v.y*v.y + v.z*v.z + v.w*v.w;
        ss += __shfl_xor(ss, 1);
        ss += __shfl_xor(ss, 2);
        ss += __shfl_xor(ss, 4);
        ss += __shfl_xor(ss, 8);
        ss += __shfl_xor(ss, 16);
        if ((lane & 31) == 0) sC2[row] = ss;
    }
    __syncthreads();
    if (tid < NK) {
        float s = Sg[tid];
        sST[tid] = make_float2(s, s * sC2[tid]);
    }
    // (barrier (A) of chunk 0 orders sST before first softmax use)

    f32x4 eacc[2][8];
    #pragma unroll
    for (int i = 0; i < 2; ++i)
        #pragma unroll
        for (int j = 0; j < 8; ++j)
            eacc[i][j] = (f32x4){0.f, 0.f, 0.f, 0.f};
    f32x4 cntacc[2];
    cntacc[0] = (f32x4){0.f, 0.f, 0.f, 0.f};
    cntacc[1] = (f32x4){0.f, 0.f, 0.f, 0.f};

    CU one8;
    #pragma unroll
    for (int j = 0; j < 8; ++j) one8.u[j] = 0x3F80;  // bf16 1.0

    const float* Xb = Xg + (size_t)b * (NN * ND);
    const int rloc = wave * 16 + l15;   // chunk-local row this lane stages

    // software pipeline: raw[] holds next chunk's ks=0,1 halves (4 float4)
    float4 raw[4];
    {
        const float* rp0 = Xb + (size_t)(bg * TT * NC + rloc) * ND;
        raw[0] = *reinterpret_cast<const float4*>(rp0 + quad * 8);
        raw[1] = *reinterpret_cast<const float4*>(rp0 + quad * 8 + 4);
        raw[2] = *reinterpret_cast<const float4*>(rp0 + 32 + quad * 8);
        raw[3] = *reinterpret_cast<const float4*>(rp0 + 32 + quad * 8 + 4);
    }

    #pragma unroll 1
    for (int t = 0; t < TT; ++t) {
        const int chunk = bg * TT + t;
        const float* rp = Xb + (size_t)(chunk * NC + rloc) * ND;

        // ---- ks=2,3 loads issued first (latency overlapped w/ conversions) ----
        float4 va2 = *reinterpret_cast<const float4*>(rp + 64 + quad * 8);
        float4 vb2 = *reinterpret_cast<const float4*>(rp + 64 + quad * 8 + 4);
        float4 va3 = *reinterpret_cast<const float4*>(rp + 96 + quad * 8);
        float4 vb3 = *reinterpret_cast<const float4*>(rp + 96 + quad * 8 + 4);

        CU cu[4];
        float x2 = 0.f;
        #pragma unroll
        for (int ks = 0; ks < 2; ++ks) {
            float4 va = raw[ks * 2], vb = raw[ks * 2 + 1];
            x2 += va.x*va.x + va.y*va.y + va.z*va.z + va.w*va.w;
            x2 += vb.x*vb.x + vb.y*vb.y + vb.z*vb.z + vb.w*vb.w;
            cu[ks].b[0] = (__bf16)va.x; cu[ks].b[1] = (__bf16)va.y;
            cu[ks].b[2] = (__bf16)va.z; cu[ks].b[3] = (__bf16)va.w;
            cu[ks].b[4] = (__bf16)vb.x; cu[ks].b[5] = (__bf16)vb.y;
            cu[ks].b[6] = (__bf16)vb.z; cu[ks].b[7] = (__bf16)vb.w;
        }
        {
            x2 += va2.x*va2.x + va2.y*va2.y + va2.z*va2.z + va2.w*va2.w;
            x2 += vb2.x*vb2.x + vb2.y*vb2.y + vb2.z*vb2.z + vb2.w*vb2.w;
            cu[2].b[0] = (__bf16)va2.x; cu[2].b[1] = (__bf16)va2.y;
            cu[2].b[2] = (__bf16)va2.z; cu[2].b[3] = (__bf16)va2.w;
            cu[2].b[4] = (__bf16)vb2.x; cu[2].b[5] = (__bf16)vb2.y;
            cu[2].b[6] = (__bf16)vb2.z; cu[2].b[7] = (__bf16)vb2.w;
            x2 += va3.x*va3.x + va3.y*va3.y + va3.z*va3.z + va3.w*va3.w;
            x2 += vb3.x*vb3.x + vb3.y*vb3.y + vb3.z*vb3.z + vb3.w*vb3.w;
            cu[3].b[0] = (__bf16)va3.x; cu[3].b[1] = (__bf16)va3.y;
            cu[3].b[2] = (__bf16)va3.z; cu[3].b[3] = (__bf16)va3.w;
            cu[3].b[4] = (__bf16)vb3.x; cu[3].b[5] = (__bf16)vb3.y;
            cu[3].b[6] = (__bf16)vb3.z; cu[3].b[7] = (__bf16)vb3.w;
        }
        x2 += __shfl_xor(x2, 16);
        x2 += __shfl_xor(x2, 32);       // full X2 of row (chunk*64 + rloc)

        __syncthreads();                // (A) prev chunk's matmul2 reads done

        // ---- prefetch next chunk's ks=0,1 (in flight until barrier B) ----
        if (t + 1 < TT) {
            const float* rpn = rp + (size_t)NC * ND;
            raw[0] = *reinterpret_cast<const float4*>(rpn + quad * 8);
            raw[1] = *reinterpret_cast<const float4*>(rpn + quad * 8 + 4);
            raw[2] = *reinterpret_cast<const float4*>(rpn + 32 + quad * 8);
            raw[3] = *reinterpret_cast<const float4*>(rpn + 32 + quad * 8 + 4);
        }

        // ---- scatter X^T (swizzled to dodge bank conflicts) ----
        #pragma unroll
        for (int ks = 0; ks < 4; ++ks) {
            #pragma unroll
            for (int j = 0; j < 8; ++j) {
                int d  = ks * 32 + quad * 8 + j;
                int rs = rloc ^ (((d >> 3) & 3) << 3);
                sXT[d * XTP + rs] = cu[ks].u[j];
            }
        }

        // ---- matmul1 (SWAPPED): D^T[n][cw] = X x C^T ----
        // A = cu (lane's own row, registers, free); B = sCb bytes as C^T-frags.
        // D-frag: lane holds (n = quad*4+r, cw = mt*16+l15).
        f32x4 dacc[8];
        #pragma unroll
        for (int mt = 0; mt < 8; ++mt) {
            f32x4 acc = (f32x4){0.f, 0.f, 0.f, 0.f};
            #pragma unroll
            for (int ks = 0; ks < 4; ++ks) {
                bf16x8 cf = *reinterpret_cast<const bf16x8*>(
                    &sCb[(mt * 16 + l15) * CBP + ks * 32 + quad * 8]);
                acc = __builtin_amdgcn_mfma_f32_16x16x32_bf16(cu[ks].v, cf, acc, 0, 0, 0);
            }
            dacc[mt] = acc;
        }

        // ---- softmax over cw, NO max pass (S<=0 => D<=0 => exp in (0,1]) ----
        // lane needs x2 of rows wave*16 + quad*4 + r (held by lanes l15=quad*4+r)
        float x2r0 = __shfl(x2, quad * 4 + 0);
        float x2r1 = __shfl(x2, quad * 4 + 1);
        float x2r2 = __shfl(x2, quad * 4 + 2);
        float x2r3 = __shfl(x2, quad * 4 + 3);
        float ls0 = 0.f, ls1 = 0.f, ls2 = 0.f, ls3 = 0.f;
        #pragma unroll
        for (int mt = 0; mt < 8; ++mt) {
            float2 sv = sST[mt * 16 + l15];   // broadcast across quads, conflict-free
            float e0 = __expf(sv.x * fmaf(-2.f, dacc[mt][0], x2r0) + sv.y);
            float e1 = __expf(sv.x * fmaf(-2.f, dacc[mt][1], x2r1) + sv.y);
            float e2 = __expf(sv.x * fmaf(-2.f, dacc[mt][2], x2r2) + sv.y);
            float e3 = __expf(sv.x * fmaf(-2.f, dacc[mt][3], x2r3) + sv.y);
            dacc[mt][0] = e0; dacc[mt][1] = e1;
            dacc[mt][2] = e2; dacc[mt][3] = e3;
            ls0 += e0; ls1 += e1; ls2 += e2; ls3 += e3;
        }
        // reduce over cw: mt handled above, l15 axis via xor-tree (quads are
        // distinct n, must NOT mix -> masks 1,2,4,8 only)
        #pragma unroll
        for (int sh = 1; sh < 16; sh <<= 1) {
            ls0 += __shfl_xor(ls0, sh);
            ls1 += __shfl_xor(ls1, sh);
            ls2 += __shfl_xor(ls2, sh);
            ls3 += __shfl_xor(ls3, sh);
        }
        const float inv0 = 1.0f / ls0, inv1 = 1.0f / ls1;
        const float inv2 = 1.0f / ls2, inv3 = 1.0f / ls3;

        // ---- A -> LDS: 4 consecutive n per lane -> packed ds_write_b64 ----
        #pragma unroll
        for (int mt = 0; mt < 8; ++mt) {
            HH4 h;
            h.b[0] = (__bf16)(dacc[mt][0] * inv0);
            h.b[1] = (__bf16)(dacc[mt][1] * inv1);
            h.b[2] = (__bf16)(dacc[mt][2] * inv2);
            h.b[3] = (__bf16)(dacc[mt][3] * inv3);
            *reinterpret_cast<ushort4*>(
                &sAt[(mt * 16 + l15) * ATP + wave * 16 + quad * 4]) = h.s;
        }

        __syncthreads();                // (B) X^T and A^T visible to all waves

        // ---- matmul2: E[cw][d] += A x X, dt-outer so each b-frag is read
        //      ONCE and reused for both mt2 (b128 reads 32 -> 16/wave/chunk).
        bf16x8 a0[2], a1[2];
        #pragma unroll
        for (int mt2 = 0; mt2 < 2; ++mt2) {
            const int cwrow = wave * 32 + mt2 * 16 + l15;
            a0[mt2] = *reinterpret_cast<const bf16x8*>(&sAt[cwrow * ATP + quad * 8]);
            a1[mt2] = *reinterpret_cast<const bf16x8*>(&sAt[cwrow * ATP + 32 + quad * 8]);
            // count[cw] += sum_n A[cw][n]: B = ones -> D[row][col] indep of col
            cntacc[mt2] = __builtin_amdgcn_mfma_f32_16x16x32_bf16(a0[mt2], one8.v, cntacc[mt2], 0, 0, 0);
            cntacc[mt2] = __builtin_amdgcn_mfma_f32_16x16x32_bf16(a1[mt2], one8.v, cntacc[mt2], 0, 0, 0);
        }
        #pragma unroll
        for (int dt = 0; dt < 8; ++dt) {
            const int drow = dt * 16 + l15;
            const int sw = ((drow >> 3) & 3) << 3;
            const unsigned short* xp = &sXT[drow * XTP];
            bf16x8 b0 = *reinterpret_cast<const bf16x8*>(&xp[(quad * 8) ^ sw]);
            bf16x8 b1 = *reinterpret_cast<const bf16x8*>(&xp[(32 + quad * 8) ^ sw]);
            #pragma unroll
            for (int mt2 = 0; mt2 < 2; ++mt2) {
                eacc[mt2][dt] = __builtin_amdgcn_mfma_f32_16x16x32_bf16(a0[mt2], b0, eacc[mt2][dt], 0, 0, 0);
                eacc[mt2][dt] = __builtin_amdgcn_mfma_f32_16x16x32_bf16(a1[mt2], b1, eacc[mt2][dt], 0, 0, 0);
            }
        }
    }

    // ---- epilogue: bf16 partial (E_part - count*C) to private ws slice ----
    // cntacc[mt2][r] holds count for cw = wave*32+mt2*16+quad*4+r (all l15 lanes)
    unsigned short* P = Pg + (size_t)bid * (NK * ND);
    #pragma unroll
    for (int mt2 = 0; mt2 < 2; ++mt2) {
        #pragma unroll
        for (int r = 0; r < 4; ++r) {
            const int cw = wave * 32 + mt2 * 16 + quad * 4 + r;
            const float cc = cntacc[mt2][r];
            const float* crow = Cg + cw * ND;
            #pragma unroll
            for (int dt = 0; dt < 8; ++dt) {
                const int d = dt * 16 + l15;
                *reinterpret_cast<__bf16*>(&P[cw * ND + d]) =
                    (__bf16)(eacc[mt2][dt][r] - cc * crow[d]);
            }
        }
    }
}

// ---------------- kernel 2: partial reduction ----------------
// r9: thread-per-float2, 1024 waves (4/CU), unroll 16 -> ~16KB/CU in flight.
__global__ __launch_bounds__(128) void vq_reduce(
    const unsigned short* __restrict__ Pg, float* __restrict__ Eg)
{
    const int g  = blockIdx.x * 128 + threadIdx.x;   // 0..65535
    const int b  = g >> 13;                          // 8192 float2 per batch
    const int i2 = g & 8191;
    const unsigned short* base = Pg + (size_t)(b * BPB) * (NK * ND) + i2 * 2;
    float a0 = 0.f, a1 = 0.f;
    #pragma unroll 16
    for (int j = 0; j < BPB; ++j) {
        ushort2 v = *reinterpret_cast<const ushort2*>(base + (size_t)j * (NK * ND));
        a0 += bf2f(v.x); a1 += bf2f(v.y);
    }
    float2 o; o.x = a0; o.y = a1;
    *reinterpret_cast<float2*>(Eg + (size_t)b * (NK * ND) + i2 * 2) = o;
}

extern "C" void kernel_launch(void* const* d_in, const int* in_sizes, int n_in,
                              void* d_out, int out_size, void* d_ws, size_t ws_size,
                              hipStream_t stream) {
    const float* X = (const float*)d_in[0];
    const float* C = (const float*)d_in[1];
    const float* S = (const float*)d_in[2];
    float* E = (float*)d_out;
    (void)n_in; (void)in_sizes; (void)out_size; (void)ws_size;

    // ws layout: bf16 partials, 512 * 16384 u16 = 16 MiB.
    unsigned short* P = (unsigned short*)d_ws;

    hipLaunchKernelGGL(vq_main,   dim3(512), dim3(256), 0, stream, X, C, S, P);
    hipLaunchKernelGGL(vq_reduce, dim3(512), dim3(128), 0, stream, P, E);
}